// Round 7
// baseline (5210.064 us; speedup 1.0000x reference)
//
#include <hip/hip_runtime.h>
#include <math.h>

// KDE via GEMM trick, v7: occupancy-first (4 waves/SIMD), LDS-free fp16 MFMA.
//   density[i] = (1/M) * sum_j exp2(-C2*sq_ij - log2(M))
//   sq_ij = |x_i|^2 + |d_j|^2 - 2*dot(x_i,d_j)
//
// ROUND-6 EVIDENCE: v6 (128x256 tile, (256,2)) is latency-bound: MfmaUtil
// 11.7 / VALUBusy 25 / occupancy 17.6% — only 2 waves/SIMD to cover the
// MFMA-chain + exp2 dependent path, and 2048 blocks at 2/CU = 4 gens of
// tail. VGPR_Count=128 shows per-wave state is the occupancy limiter.
//
// v7: wave = 16 rows (af = 4 frags = 16 VGPR), block = 4 waves = 64 rows
// x 1024 cols. Grid = 128 x 8 = 1024 blocks = EXACTLY 4 blocks/CU at
// __launch_bounds__(256,4) (VGPR cap 128; est. ~90 live -> no spill), one
// generation, zero tail, 16 waves/CU. 64 iters/wave: register-double-
// buffered B col-tile prefetch (4 coalesced dwordx4), 4-MFMA chain,
// 4-element fused exp2 epilogue. No LDS, no barriers, no conversions
// (prep emits fragment-ready fp16 + pre-scaled norms; prep is ~free —
// the ~50 us total-vs-main gap is harness-fixed, r2..r6 evidence).
//
// Fragment mappings (verified end-to-end rounds 2-6):
//   A: lane holds A[m=lane&15][k=(lane>>4)*8+j]
//   B: lane holds B^T row-major: col=lane&15, k=(lane>>4)*8+j
//   C/D: col=lane&15, row=(lane>>4)*4+reg
// fp16 single-pass accuracy verified r4-r6: absmax 2.8e-17 vs 2.4e-16 thr.

#define D_DIM 128

typedef _Float16 f16x8 __attribute__((ext_vector_type(8)));
typedef _Float16 f16x4 __attribute__((ext_vector_type(4)));
typedef __attribute__((ext_vector_type(4))) float f32x4;

#define C2F ((float)(0.5 / 2.50662827463100050242 * 1.44269504088896340736))

// ---- prep: fp32 -> fp16 fragment-major + pre-scaled norms ----------------
// Thread (row, seg 0..31) handles 4 consecutive fp32 of one row.
// k = seg*4 -> kc=seg>>3, q=(seg>>1)&3, j0=(seg&1)*4; store 8 B at
// halves offset ((t*4+kc)*64 + q*16 + r)*8 + j0   (t = row>>4, r = row&15).
__global__ __launch_bounds__(256)
void prep_kernel(const float* __restrict__ x, const float* __restrict__ data,
                 _Float16* __restrict__ xf, _Float16* __restrict__ df,
                 float* __restrict__ xn_u, float* __restrict__ dn_s,
                 int xThreads, float negLogM) {
    const int gid = blockIdx.x * 256 + threadIdx.x;
    const int which = (gid >= xThreads);
    const int id = which ? (gid - xThreads) : gid;
    const int row = id >> 5, seg = id & 31;
    const float* src = which ? data : x;
    _Float16* dst = which ? df : xf;

    const float4 v = *(const float4*)&src[(size_t)row * D_DIM + seg * 4];

    const int t = row >> 4, r = row & 15;
    const int kc = seg >> 3, q = (seg >> 1) & 3, j0 = (seg & 1) * 4;
    f16x4 h;
    h[0] = (_Float16)v.x; h[1] = (_Float16)v.y;
    h[2] = (_Float16)v.z; h[3] = (_Float16)v.w;
    *(f16x4*)&dst[((size_t)(t * 4 + kc) * 64 + q * 16 + r) * 8 + j0] = h;

    float nrm = fmaf(v.x, v.x, fmaf(v.y, v.y, fmaf(v.z, v.z, v.w * v.w)));
#pragma unroll
    for (int off = 1; off < 32; off <<= 1) nrm += __shfl_xor(nrm, off, 64);
    if (seg == 0) {
        if (which) dn_s[row] = -C2F * nrm;
        else       xn_u[row] = fmaf(-C2F, nrm, negLogM);
    }
}

// ---- main: 4 waves x 16 rows, 64 col-tiles, LDS/barrier-free -------------
__global__ __launch_bounds__(256, 4)
void kde_f16v7(const _Float16* __restrict__ xf, const _Float16* __restrict__ df,
               const float* __restrict__ xn_u, const float* __restrict__ dn_s,
               float* __restrict__ out, int colGroups, int tilesPerGroup) {
    const int tid  = threadIdx.x;
    const int lane = tid & 63;
    const int w    = tid >> 6;
    const int q    = lane >> 4;
    const int r    = lane & 15;

    const int bid = blockIdx.x;
    const int cg  = bid % colGroups;
    const int rb  = bid / colGroups;
    const int rowBase  = rb * 64 + w * 16;     // this wave's 16 rows
    const int colTile0 = cg * tilesPerGroup;   // first 16-col tile

    const float twoC2 = 2.0f * C2F;

    // A fragments: 4 coalesced dwordx4 loads, once. Global row-tile index:
    const int tG = rb * 4 + w;
    f16x8 af[4];
#pragma unroll
    for (int kc = 0; kc < 4; ++kc)
        af[kc] = *(const f16x8*)&xf[((size_t)(tG * 4 + kc) * 64 + lane) * 8];

    // Row constants for this lane's 4 accumulator rows (row = q*4+p).
    const f32x4 u = *(const f32x4*)&xn_u[rowBase + q * 4];

    f32x4 srow = (f32x4){0.f, 0.f, 0.f, 0.f};

    // Register double-buffered B prefetch.
    f16x8 bf[2][4];
    float dnv[2];
    {
        const int ctG = colTile0;
#pragma unroll
        for (int kc = 0; kc < 4; ++kc)
            bf[0][kc] = *(const f16x8*)&df[((size_t)(ctG * 4 + kc) * 64 + lane) * 8];
        dnv[0] = dn_s[ctG * 16 + r];
    }

#pragma unroll 4
    for (int it = 0; it < tilesPerGroup; ++it) {
        const int cur = it & 1;
        if (it + 1 < tilesPerGroup) {
            const int ctG = colTile0 + it + 1;
#pragma unroll
            for (int kc = 0; kc < 4; ++kc)
                bf[cur ^ 1][kc] = *(const f16x8*)&df[((size_t)(ctG * 4 + kc) * 64 + lane) * 8];
            dnv[cur ^ 1] = dn_s[ctG * 16 + r];
        }

        f32x4 acc = (f32x4){0.f, 0.f, 0.f, 0.f};
#pragma unroll
        for (int kc = 0; kc < 4; ++kc)
            acc = __builtin_amdgcn_mfma_f32_16x16x32_f16(af[kc], bf[cur][kc], acc, 0, 0, 0);

        const float d0 = dnv[cur];
        srow[0] += __builtin_amdgcn_exp2f(fmaf(twoC2, acc[0], u[0] + d0));
        srow[1] += __builtin_amdgcn_exp2f(fmaf(twoC2, acc[1], u[1] + d0));
        srow[2] += __builtin_amdgcn_exp2f(fmaf(twoC2, acc[2], u[2] + d0));
        srow[3] += __builtin_amdgcn_exp2f(fmaf(twoC2, acc[3], u[3] + d0));
    }

    // Reduce srow over the 16 col-lanes (r) and accumulate to out.
#pragma unroll
    for (int p = 0; p < 4; ++p) {
        float s = srow[p];
        s += __shfl_xor(s, 1, 64);
        s += __shfl_xor(s, 2, 64);
        s += __shfl_xor(s, 4, 64);
        s += __shfl_xor(s, 8, 64);
        if (r == 0)
            atomicAdd(&out[rowBase + q * 4 + p], s);
    }
}

// ---------------- fallback: round-1 VALU kernel (any size, no ws) ---------
#define BN 128
#define BM 128
#define KT 32
#define LDSS 132

__global__ __launch_bounds__(256, 4)
void kde_valu(const float* __restrict__ x, const float* __restrict__ data,
              float* __restrict__ out, int N, int M) {
    __shared__ float xs[KT][LDSS];
    __shared__ float dsh[KT][LDSS];
    __shared__ float xn_s[BN];
    __shared__ float dn_s[BM];
    const int tid = threadIdx.x;
    const int ty = tid >> 4, tx = tid & 15;
    const int rowBase = blockIdx.y * BN, colBase = blockIdx.x * BM;
    float acc[8][8];
#pragma unroll
    for (int i = 0; i < 8; ++i)
#pragma unroll
        for (int j = 0; j < 8; ++j) acc[i][j] = 0.0f;
    float normAcc = 0.0f;
    for (int kc = 0; kc < D_DIM; kc += KT) {
        __syncthreads();
#pragma unroll
        for (int i = 0; i < 4; ++i) {
            const int idx = tid + i * 256;
            const int row = idx >> 3, kq = idx & 7;
            const float4 v = *(const float4*)&x[(size_t)(rowBase + row) * D_DIM + kc + kq * 4];
            xs[kq * 4 + 0][row] = v.x; xs[kq * 4 + 1][row] = v.y;
            xs[kq * 4 + 2][row] = v.z; xs[kq * 4 + 3][row] = v.w;
            const float4 wv = *(const float4*)&data[(size_t)(colBase + row) * D_DIM + kc + kq * 4];
            dsh[kq * 4 + 0][row] = wv.x; dsh[kq * 4 + 1][row] = wv.y;
            dsh[kq * 4 + 2][row] = wv.z; dsh[kq * 4 + 3][row] = wv.w;
        }
        __syncthreads();
        {
            const float* col = (tid < 128) ? &xs[0][tid] : &dsh[0][tid - 128];
#pragma unroll
            for (int k = 0; k < KT; ++k) { const float v = col[k * LDSS]; normAcc = fmaf(v, v, normAcc); }
        }
#pragma unroll
        for (int k = 0; k < KT; ++k) {
            float a[8], b[8];
            *(float4*)&a[0] = *(const float4*)&xs[k][ty * 8];
            *(float4*)&a[4] = *(const float4*)&xs[k][ty * 8 + 4];
            *(float4*)&b[0] = *(const float4*)&dsh[k][tx * 4];
            *(float4*)&b[4] = *(const float4*)&dsh[k][64 + tx * 4];
#pragma unroll
            for (int i = 0; i < 8; ++i)
#pragma unroll
                for (int j = 0; j < 8; ++j) acc[i][j] = fmaf(a[i], b[j], acc[i][j]);
        }
    }
    if (tid < 128) xn_s[tid] = normAcc; else dn_s[tid - 128] = normAcc;
    __syncthreads();
    const float C2 = C2F;
    const float negLogM = -log2f((float)M);
#pragma unroll
    for (int i = 0; i < 8; ++i) {
        const int row = ty * 8 + i;
        const float xnr = xn_s[row];
        float s = 0.0f;
#pragma unroll
        for (int j = 0; j < 8; ++j) {
            const int col = (j < 4) ? (tx * 4 + j) : (64 + tx * 4 + (j - 4));
            const float sq = xnr + dn_s[col] - 2.0f * acc[i][j];
            s += exp2f(fmaf(-C2, sq, negLogM));
        }
#pragma unroll
        for (int off = 1; off < 16; off <<= 1) s += __shfl_xor(s, off, 64);
        if (tx == 0) atomicAdd(&out[rowBase + row], s);
    }
}

extern "C" void kernel_launch(void* const* d_in, const int* in_sizes, int n_in,
                              void* d_out, int out_size, void* d_ws, size_t ws_size,
                              hipStream_t stream) {
    const float* x    = (const float*)d_in[0];
    const float* data = (const float*)d_in[1];
    float* out = (float*)d_out;
    const int N = in_sizes[0] / D_DIM;
    const int M = in_sizes[1] / D_DIM;

    hipMemsetAsync(d_out, 0, (size_t)out_size * sizeof(float), stream);

    const size_t need = (size_t)(N + M) * D_DIM * 2 + (size_t)(N + M) * 4;
    if (ws_size < need || (N & 63) || (M & 1023)) {
        if (!(N & 127) && !(M & 127)) {
            dim3 grid(M / BM, N / BN);
            kde_valu<<<grid, 256, 0, stream>>>(x, data, out, N, M);
        } else {
            dim3 grid(M / BM, N / BN);  // harness sizes are fixed; defensive only
            kde_valu<<<grid, 256, 0, stream>>>(x, data, out, N, M);
        }
        return;
    }

    _Float16* xf = (_Float16*)d_ws;
    _Float16* df = xf + (size_t)N * D_DIM;
    float* xn_u = (float*)(df + (size_t)M * D_DIM);
    float* dn_s = xn_u + N;

    const float negLogM = -log2f((float)M);
    const int xThreads = N * 32;
    const int totThreads = (N + M) * 32;
    prep_kernel<<<totThreads / 256, 256, 0, stream>>>(x, data, xf, df, xn_u, dn_s,
                                                      xThreads, negLogM);

    const int colGroups = M / 1024;          // 1024 cols per group
    const int tilesPerGroup = 64;            // 64 x 16-col tiles
    const int rowBlocks = N / 64;
    kde_f16v7<<<rowBlocks * colGroups, 256, 0, stream>>>(xf, df, xn_u, dn_s, out,
                                                         colGroups, tilesPerGroup);
}

// Round 8
// 251.772 us; speedup vs baseline: 20.6936x; 20.6936x over previous
//
#include <hip/hip_runtime.h>
#include <math.h>

// KDE via GEMM trick, v8: v7's occupancy shape + register-safe double buffer.
//   density[i] = (1/M) * sum_j exp2(-C2*sq_ij - log2(M))
//   sq_ij = |x_i|^2 + |d_j|^2 - 2*dot(x_i,d_j)
//
// ROUND-7 LESSON (counters: VGPR_Count collapsed 128->64, MfmaUtil 0.13,
// dur 100x): runtime trip count + `#pragma unroll 4` left bf[2][4]/dnv[2]
// as dynamically-indexed private arrays -> scratch (small footprint, so it
// hid in L1/L2 and never showed in HBM FETCH/WRITE). Double-buffer state
// MUST be fully-unrolled-constant-indexed or hand-named.
//
// v8: identical tiling to v7 — wave = 16 rows (af = 4 frags = 16 VGPR),
// block = 4 waves = 64 rows x 1024 cols, grid = 128x8 = 1024 blocks =
// exactly 4 blocks/CU at __launch_bounds__(256,4), one generation, no
// tail, 16 waves/CU. Iteration loop is COMPILE-TIME 64, hand-unrolled x2
// with two NAMED register buffers (b0[], b1[], constant indices only).
// No LDS, no barriers, no conversions (prep emits fragment-ready fp16 +
// pre-scaled norms; prep is ~free — ~50 us total-vs-main gap is
// harness-fixed, r2..r6 evidence).
//
// Fragment mappings (verified end-to-end rounds 2-6):
//   A: lane holds A[m=lane&15][k=(lane>>4)*8+j]
//   B: lane holds B^T row-major: col=lane&15, k=(lane>>4)*8+j
//   C/D: col=lane&15, row=(lane>>4)*4+reg
// fp16 single-pass accuracy verified r4-r6: absmax 2.8e-17 vs 2.4e-16 thr.

#define D_DIM 128
#define TPG   64   // 16-col tiles per col-group (1024 cols) — compile-time

typedef _Float16 f16x8 __attribute__((ext_vector_type(8)));
typedef _Float16 f16x4 __attribute__((ext_vector_type(4)));
typedef __attribute__((ext_vector_type(4))) float f32x4;

#define C2F ((float)(0.5 / 2.50662827463100050242 * 1.44269504088896340736))

// ---- prep: fp32 -> fp16 fragment-major + pre-scaled norms ----------------
// Thread (row, seg 0..31) handles 4 consecutive fp32 of one row.
// k = seg*4 -> kc=seg>>3, q=(seg>>1)&3, j0=(seg&1)*4; store 8 B at
// halves offset ((t*4+kc)*64 + q*16 + r)*8 + j0   (t = row>>4, r = row&15).
__global__ __launch_bounds__(256)
void prep_kernel(const float* __restrict__ x, const float* __restrict__ data,
                 _Float16* __restrict__ xf, _Float16* __restrict__ df,
                 float* __restrict__ xn_u, float* __restrict__ dn_s,
                 int xThreads, float negLogM) {
    const int gid = blockIdx.x * 256 + threadIdx.x;
    const int which = (gid >= xThreads);
    const int id = which ? (gid - xThreads) : gid;
    const int row = id >> 5, seg = id & 31;
    const float* src = which ? data : x;
    _Float16* dst = which ? df : xf;

    const float4 v = *(const float4*)&src[(size_t)row * D_DIM + seg * 4];

    const int t = row >> 4, r = row & 15;
    const int kc = seg >> 3, q = (seg >> 1) & 3, j0 = (seg & 1) * 4;
    f16x4 h;
    h[0] = (_Float16)v.x; h[1] = (_Float16)v.y;
    h[2] = (_Float16)v.z; h[3] = (_Float16)v.w;
    *(f16x4*)&dst[((size_t)(t * 4 + kc) * 64 + q * 16 + r) * 8 + j0] = h;

    float nrm = fmaf(v.x, v.x, fmaf(v.y, v.y, fmaf(v.z, v.z, v.w * v.w)));
#pragma unroll
    for (int off = 1; off < 32; off <<= 1) nrm += __shfl_xor(nrm, off, 64);
    if (seg == 0) {
        if (which) dn_s[row] = -C2F * nrm;
        else       xn_u[row] = fmaf(-C2F, nrm, negLogM);
    }
}

// ---- main: 4 waves x 16 rows, 64 col-tiles, LDS/barrier-free -------------
__global__ __launch_bounds__(256, 4)
void kde_f16v8(const _Float16* __restrict__ xf, const _Float16* __restrict__ df,
               const float* __restrict__ xn_u, const float* __restrict__ dn_s,
               float* __restrict__ out, int colGroups) {
    const int tid  = threadIdx.x;
    const int lane = tid & 63;
    const int w    = tid >> 6;
    const int q    = lane >> 4;
    const int r    = lane & 15;

    const int bid = blockIdx.x;
    const int cg  = bid % colGroups;
    const int rb  = bid / colGroups;
    const int rowBase  = rb * 64 + w * 16;   // this wave's 16 rows
    const int colTile0 = cg * TPG;           // first 16-col tile

    const float twoC2 = 2.0f * C2F;

    // A fragments: 4 coalesced dwordx4 loads, once.
    const int tG = rb * 4 + w;
    f16x8 af[4];
#pragma unroll
    for (int kc = 0; kc < 4; ++kc)
        af[kc] = *(const f16x8*)&xf[((size_t)(tG * 4 + kc) * 64 + lane) * 8];

    // Row constants for this lane's 4 accumulator rows (row = q*4+p).
    const f32x4 u = *(const f32x4*)&xn_u[rowBase + q * 4];

    f32x4 srow = (f32x4){0.f, 0.f, 0.f, 0.f};

    // Hand-named register double buffers (constant indices only -> SROA).
    f16x8 b0[4], b1[4];
    float d0, d1;

    const _Float16* dbase = &df[(size_t)colTile0 * 4 * 64 * 8];
#pragma unroll
    for (int kc = 0; kc < 4; ++kc)
        b0[kc] = *(const f16x8*)&dbase[((size_t)kc * 64 + lane) * 8];
    d0 = dn_s[colTile0 * 16 + r];

#pragma unroll
    for (int it = 0; it < TPG; it += 2) {
        // ---- even tile: compute with b0, prefetch it+1 into b1 ----
        if (it + 1 < TPG) {
            const _Float16* p = &dbase[(size_t)(it + 1) * 4 * 64 * 8];
#pragma unroll
            for (int kc = 0; kc < 4; ++kc)
                b1[kc] = *(const f16x8*)&p[((size_t)kc * 64 + lane) * 8];
            d1 = dn_s[(colTile0 + it + 1) * 16 + r];
        }
        {
            f32x4 acc = (f32x4){0.f, 0.f, 0.f, 0.f};
#pragma unroll
            for (int kc = 0; kc < 4; ++kc)
                acc = __builtin_amdgcn_mfma_f32_16x16x32_f16(af[kc], b0[kc], acc, 0, 0, 0);
            srow[0] += __builtin_amdgcn_exp2f(fmaf(twoC2, acc[0], u[0] + d0));
            srow[1] += __builtin_amdgcn_exp2f(fmaf(twoC2, acc[1], u[1] + d0));
            srow[2] += __builtin_amdgcn_exp2f(fmaf(twoC2, acc[2], u[2] + d0));
            srow[3] += __builtin_amdgcn_exp2f(fmaf(twoC2, acc[3], u[3] + d0));
        }
        // ---- odd tile: compute with b1, prefetch it+2 into b0 ----
        if (it + 2 < TPG) {
            const _Float16* p = &dbase[(size_t)(it + 2) * 4 * 64 * 8];
#pragma unroll
            for (int kc = 0; kc < 4; ++kc)
                b0[kc] = *(const f16x8*)&p[((size_t)kc * 64 + lane) * 8];
            d0 = dn_s[(colTile0 + it + 2) * 16 + r];
        }
        {
            f32x4 acc = (f32x4){0.f, 0.f, 0.f, 0.f};
#pragma unroll
            for (int kc = 0; kc < 4; ++kc)
                acc = __builtin_amdgcn_mfma_f32_16x16x32_f16(af[kc], b1[kc], acc, 0, 0, 0);
            srow[0] += __builtin_amdgcn_exp2f(fmaf(twoC2, acc[0], u[0] + d1));
            srow[1] += __builtin_amdgcn_exp2f(fmaf(twoC2, acc[1], u[1] + d1));
            srow[2] += __builtin_amdgcn_exp2f(fmaf(twoC2, acc[2], u[2] + d1));
            srow[3] += __builtin_amdgcn_exp2f(fmaf(twoC2, acc[3], u[3] + d1));
        }
    }

    // Reduce srow over the 16 col-lanes (r) and accumulate to out.
#pragma unroll
    for (int p = 0; p < 4; ++p) {
        float s = srow[p];
        s += __shfl_xor(s, 1, 64);
        s += __shfl_xor(s, 2, 64);
        s += __shfl_xor(s, 4, 64);
        s += __shfl_xor(s, 8, 64);
        if (r == 0)
            atomicAdd(&out[rowBase + q * 4 + p], s);
    }
}

// ---------------- fallback: round-1 VALU kernel (any size, no ws) ---------
#define BN 128
#define BM 128
#define KT 32
#define LDSS 132

__global__ __launch_bounds__(256, 4)
void kde_valu(const float* __restrict__ x, const float* __restrict__ data,
              float* __restrict__ out, int N, int M) {
    __shared__ float xs[KT][LDSS];
    __shared__ float dsh[KT][LDSS];
    __shared__ float xn_s[BN];
    __shared__ float dn_s[BM];
    const int tid = threadIdx.x;
    const int ty = tid >> 4, tx = tid & 15;
    const int rowBase = blockIdx.y * BN, colBase = blockIdx.x * BM;
    float acc[8][8];
#pragma unroll
    for (int i = 0; i < 8; ++i)
#pragma unroll
        for (int j = 0; j < 8; ++j) acc[i][j] = 0.0f;
    float normAcc = 0.0f;
    for (int kc = 0; kc < D_DIM; kc += KT) {
        __syncthreads();
#pragma unroll
        for (int i = 0; i < 4; ++i) {
            const int idx = tid + i * 256;
            const int row = idx >> 3, kq = idx & 7;
            const float4 v = *(const float4*)&x[(size_t)(rowBase + row) * D_DIM + kc + kq * 4];
            xs[kq * 4 + 0][row] = v.x; xs[kq * 4 + 1][row] = v.y;
            xs[kq * 4 + 2][row] = v.z; xs[kq * 4 + 3][row] = v.w;
            const float4 wv = *(const float4*)&data[(size_t)(colBase + row) * D_DIM + kc + kq * 4];
            dsh[kq * 4 + 0][row] = wv.x; dsh[kq * 4 + 1][row] = wv.y;
            dsh[kq * 4 + 2][row] = wv.z; dsh[kq * 4 + 3][row] = wv.w;
        }
        __syncthreads();
        {
            const float* col = (tid < 128) ? &xs[0][tid] : &dsh[0][tid - 128];
#pragma unroll
            for (int k = 0; k < KT; ++k) { const float v = col[k * LDSS]; normAcc = fmaf(v, v, normAcc); }
        }
#pragma unroll
        for (int k = 0; k < KT; ++k) {
            float a[8], b[8];
            *(float4*)&a[0] = *(const float4*)&xs[k][ty * 8];
            *(float4*)&a[4] = *(const float4*)&xs[k][ty * 8 + 4];
            *(float4*)&b[0] = *(const float4*)&dsh[k][tx * 4];
            *(float4*)&b[4] = *(const float4*)&dsh[k][64 + tx * 4];
#pragma unroll
            for (int i = 0; i < 8; ++i)
#pragma unroll
                for (int j = 0; j < 8; ++j) acc[i][j] = fmaf(a[i], b[j], acc[i][j]);
        }
    }
    if (tid < 128) xn_s[tid] = normAcc; else dn_s[tid - 128] = normAcc;
    __syncthreads();
    const float C2 = C2F;
    const float negLogM = -log2f((float)M);
#pragma unroll
    for (int i = 0; i < 8; ++i) {
        const int row = ty * 8 + i;
        const float xnr = xn_s[row];
        float s = 0.0f;
#pragma unroll
        for (int j = 0; j < 8; ++j) {
            const int col = (j < 4) ? (tx * 4 + j) : (64 + tx * 4 + (j - 4));
            const float sq = xnr + dn_s[col] - 2.0f * acc[i][j];
            s += exp2f(fmaf(-C2, sq, negLogM));
        }
#pragma unroll
        for (int off = 1; off < 16; off <<= 1) s += __shfl_xor(s, off, 64);
        if (tx == 0) atomicAdd(&out[rowBase + row], s);
    }
}

extern "C" void kernel_launch(void* const* d_in, const int* in_sizes, int n_in,
                              void* d_out, int out_size, void* d_ws, size_t ws_size,
                              hipStream_t stream) {
    const float* x    = (const float*)d_in[0];
    const float* data = (const float*)d_in[1];
    float* out = (float*)d_out;
    const int N = in_sizes[0] / D_DIM;
    const int M = in_sizes[1] / D_DIM;

    hipMemsetAsync(d_out, 0, (size_t)out_size * sizeof(float), stream);

    const size_t need = (size_t)(N + M) * D_DIM * 2 + (size_t)(N + M) * 4;
    if (ws_size < need || (N & 63) || (M & 1023)) {
        dim3 grid(M / BM, N / BN);
        kde_valu<<<grid, 256, 0, stream>>>(x, data, out, N, M);
        return;
    }

    _Float16* xf = (_Float16*)d_ws;
    _Float16* df = xf + (size_t)N * D_DIM;
    float* xn_u = (float*)(df + (size_t)M * D_DIM);
    float* dn_s = xn_u + N;

    const float negLogM = -log2f((float)M);
    const int xThreads = N * 32;
    const int totThreads = (N + M) * 32;
    prep_kernel<<<totThreads / 256, 256, 0, stream>>>(x, data, xf, df, xn_u, dn_s,
                                                      xThreads, negLogM);

    const int colGroups = M / 1024;          // 1024 cols per group, TPG=64 tiles
    const int rowBlocks = N / 64;
    kde_f16v8<<<rowBlocks * colGroups, 256, 0, stream>>>(xf, df, xn_u, dn_s, out,
                                                         colGroups);
}

// Round 9
// 87.369 us; speedup vs baseline: 59.6326x; 2.8817x over previous
//
#include <hip/hip_runtime.h>
#include <math.h>

// KDE via GEMM trick, v9: pinned waves/EU, small loop, L1-shared B stream.
//   density[i] = (1/M) * sum_j exp2(-C2*sq_ij - log2(M))
//   sq_ij = |x_i|^2 + |d_j|^2 - 2*dot(x_i,d_j)
//
// ROUND-7/8 LESSON: with __launch_bounds__(256,4) the backend TARGETED
// 8 waves/EU (VGPR_Count=64 in both rounds) and spilled the loop state
// (r8: 288 MB FETCH + 242 MB WRITE of scratch). launch_bounds' 2nd arg is
// only a MINIMUM; amdgpu_waves_per_eu(4,4) pins the target -> 128-reg
// budget. Full 64-iter unroll also ballooned live ranges -> keep the loop
// rolled (#pragma unroll 1), body = 2 tiles with hand-named b0/b1.
//
// v9 shape: block = 4 waves = 128 rows; wave = 32 rows (2 row-tiles,
// af[2][4] = 32 VGPR) -> B-fragment reuse x2 in-wave; all 4 waves walk the
// SAME col-tile sequence so 3/4 of B reads hit L1 (L2 traffic ~134 MB vs
// v8's 1.07 GB). 512 cols/group, TPG=32 compile-time; grid = 64 x 16 =
// 1024 blocks = 4/CU, one generation. No LDS, no barriers, no in-loop
// conversions (prep emits fragment-ready fp16 + pre-scaled norms; prep is
// ~free — the ~50 us total-vs-main gap is harness-fixed, r2..r6).
//
// Fragment mappings (verified end-to-end rounds 2-6):
//   A: lane holds A[m=lane&15][k=(lane>>4)*8+j]
//   B: lane holds B^T row-major: col=lane&15, k=(lane>>4)*8+j
//   C/D: col=lane&15, row=(lane>>4)*4+reg
// fp16 single-pass accuracy verified r4-r8: absmax 2.8e-17 vs 2.4e-16 thr.

#define D_DIM 128
#define TPG   32   // 16-col tiles per col-group (512 cols) — compile-time

typedef _Float16 f16x8 __attribute__((ext_vector_type(8)));
typedef _Float16 f16x4 __attribute__((ext_vector_type(4)));
typedef __attribute__((ext_vector_type(4))) float f32x4;

#define C2F ((float)(0.5 / 2.50662827463100050242 * 1.44269504088896340736))

// ---- prep: fp32 -> fp16 fragment-major + pre-scaled norms ----------------
// Thread (row, seg 0..31): k = seg*4 -> kc=seg>>3, q=(seg>>1)&3, j0=(seg&1)*4;
// 8 B store at halves offset ((t*4+kc)*64 + q*16 + r)*8 + j0.
__global__ __launch_bounds__(256)
void prep_kernel(const float* __restrict__ x, const float* __restrict__ data,
                 _Float16* __restrict__ xf, _Float16* __restrict__ df,
                 float* __restrict__ xn_u, float* __restrict__ dn_s,
                 int xThreads, float negLogM) {
    const int gid = blockIdx.x * 256 + threadIdx.x;
    const int which = (gid >= xThreads);
    const int id = which ? (gid - xThreads) : gid;
    const int row = id >> 5, seg = id & 31;
    const float* src = which ? data : x;
    _Float16* dst = which ? df : xf;

    const float4 v = *(const float4*)&src[(size_t)row * D_DIM + seg * 4];

    const int t = row >> 4, r = row & 15;
    const int kc = seg >> 3, q = (seg >> 1) & 3, j0 = (seg & 1) * 4;
    f16x4 h;
    h[0] = (_Float16)v.x; h[1] = (_Float16)v.y;
    h[2] = (_Float16)v.z; h[3] = (_Float16)v.w;
    *(f16x4*)&dst[((size_t)(t * 4 + kc) * 64 + q * 16 + r) * 8 + j0] = h;

    float nrm = fmaf(v.x, v.x, fmaf(v.y, v.y, fmaf(v.z, v.z, v.w * v.w)));
#pragma unroll
    for (int off = 1; off < 32; off <<= 1) nrm += __shfl_xor(nrm, off, 64);
    if (seg == 0) {
        if (which) dn_s[row] = -C2F * nrm;
        else       xn_u[row] = fmaf(-C2F, nrm, negLogM);
    }
}

// ---- main: 4 waves x 32 rows, shared col walk, LDS/barrier-free ----------
__global__ __launch_bounds__(256)
__attribute__((amdgpu_waves_per_eu(4, 4)))
void kde_f16v9(const _Float16* __restrict__ xf, const _Float16* __restrict__ df,
               const float* __restrict__ xn_u, const float* __restrict__ dn_s,
               float* __restrict__ out, int colGroups) {
    const int tid  = threadIdx.x;
    const int lane = tid & 63;
    const int w    = tid >> 6;
    const int q    = lane >> 4;
    const int r    = lane & 15;

    const int bid = blockIdx.x;
    const int cg  = bid % colGroups;
    const int rb  = bid / colGroups;
    const int rowBase  = rb * 128 + w * 32;  // this wave's 32 rows
    const int colTile0 = cg * TPG;

    const float twoC2 = 2.0f * C2F;

    // A fragments: 8 coalesced dwordx4 loads, once (2 row-tiles).
    f16x8 af0[4], af1[4];
    {
        const int tG0 = rb * 8 + w * 2;
#pragma unroll
        for (int kc = 0; kc < 4; ++kc) {
            af0[kc] = *(const f16x8*)&xf[((size_t)(tG0 * 4 + kc) * 64 + lane) * 8];
            af1[kc] = *(const f16x8*)&xf[((size_t)((tG0 + 1) * 4 + kc) * 64 + lane) * 8];
        }
    }

    // Row constants (row = q*4+p within each tile).
    const f32x4 u0 = *(const f32x4*)&xn_u[rowBase + q * 4];
    const f32x4 u1 = *(const f32x4*)&xn_u[rowBase + 16 + q * 4];

    f32x4 srow0 = (f32x4){0.f, 0.f, 0.f, 0.f};
    f32x4 srow1 = (f32x4){0.f, 0.f, 0.f, 0.f};

    // Hand-named register double buffers; loop kept rolled (r8 lesson).
    f16x8 b0[4], b1[4];
    float d0, d1;

    const _Float16* dbase = &df[(size_t)colTile0 * 2048];   // 4*64*8 halves/tile
    const float*    nbase = &dn_s[colTile0 * 16 + r];
#pragma unroll
    for (int kc = 0; kc < 4; ++kc)
        b0[kc] = *(const f16x8*)&dbase[((size_t)kc * 64 + lane) * 8];
    d0 = nbase[0];

#pragma unroll 1
    for (int it = 0; it < TPG; it += 2) {
        // ---- even tile: compute with b0, prefetch it+1 -> b1 ----
        {
            const _Float16* p = &dbase[(size_t)(it + 1) * 2048];
#pragma unroll
            for (int kc = 0; kc < 4; ++kc)
                b1[kc] = *(const f16x8*)&p[((size_t)kc * 64 + lane) * 8];
            d1 = nbase[(it + 1) * 16];
        }
        {
            f32x4 a0 = (f32x4){0.f, 0.f, 0.f, 0.f};
            f32x4 a1 = (f32x4){0.f, 0.f, 0.f, 0.f};
#pragma unroll
            for (int kc = 0; kc < 4; ++kc) {
                a0 = __builtin_amdgcn_mfma_f32_16x16x32_f16(af0[kc], b0[kc], a0, 0, 0, 0);
                a1 = __builtin_amdgcn_mfma_f32_16x16x32_f16(af1[kc], b0[kc], a1, 0, 0, 0);
            }
            srow0[0] += __builtin_amdgcn_exp2f(fmaf(twoC2, a0[0], u0[0] + d0));
            srow0[1] += __builtin_amdgcn_exp2f(fmaf(twoC2, a0[1], u0[1] + d0));
            srow0[2] += __builtin_amdgcn_exp2f(fmaf(twoC2, a0[2], u0[2] + d0));
            srow0[3] += __builtin_amdgcn_exp2f(fmaf(twoC2, a0[3], u0[3] + d0));
            srow1[0] += __builtin_amdgcn_exp2f(fmaf(twoC2, a1[0], u1[0] + d0));
            srow1[1] += __builtin_amdgcn_exp2f(fmaf(twoC2, a1[1], u1[1] + d0));
            srow1[2] += __builtin_amdgcn_exp2f(fmaf(twoC2, a1[2], u1[2] + d0));
            srow1[3] += __builtin_amdgcn_exp2f(fmaf(twoC2, a1[3], u1[3] + d0));
        }
        // ---- odd tile: compute with b1, prefetch it+2 -> b0 ----
        if (it + 2 < TPG) {
            const _Float16* p = &dbase[(size_t)(it + 2) * 2048];
#pragma unroll
            for (int kc = 0; kc < 4; ++kc)
                b0[kc] = *(const f16x8*)&p[((size_t)kc * 64 + lane) * 8];
            d0 = nbase[(it + 2) * 16];
        }
        {
            f32x4 a0 = (f32x4){0.f, 0.f, 0.f, 0.f};
            f32x4 a1 = (f32x4){0.f, 0.f, 0.f, 0.f};
#pragma unroll
            for (int kc = 0; kc < 4; ++kc) {
                a0 = __builtin_amdgcn_mfma_f32_16x16x32_f16(af0[kc], b1[kc], a0, 0, 0, 0);
                a1 = __builtin_amdgcn_mfma_f32_16x16x32_f16(af1[kc], b1[kc], a1, 0, 0, 0);
            }
            srow0[0] += __builtin_amdgcn_exp2f(fmaf(twoC2, a0[0], u0[0] + d1));
            srow0[1] += __builtin_amdgcn_exp2f(fmaf(twoC2, a0[1], u0[1] + d1));
            srow0[2] += __builtin_amdgcn_exp2f(fmaf(twoC2, a0[2], u0[2] + d1));
            srow0[3] += __builtin_amdgcn_exp2f(fmaf(twoC2, a0[3], u0[3] + d1));
            srow1[0] += __builtin_amdgcn_exp2f(fmaf(twoC2, a1[0], u1[0] + d1));
            srow1[1] += __builtin_amdgcn_exp2f(fmaf(twoC2, a1[1], u1[1] + d1));
            srow1[2] += __builtin_amdgcn_exp2f(fmaf(twoC2, a1[2], u1[2] + d1));
            srow1[3] += __builtin_amdgcn_exp2f(fmaf(twoC2, a1[3], u1[3] + d1));
        }
    }

    // Reduce over the 16 col-lanes (r) and accumulate to out.
#pragma unroll
    for (int p = 0; p < 4; ++p) {
        float s = srow0[p];
        s += __shfl_xor(s, 1, 64);
        s += __shfl_xor(s, 2, 64);
        s += __shfl_xor(s, 4, 64);
        s += __shfl_xor(s, 8, 64);
        if (r == 0) atomicAdd(&out[rowBase + q * 4 + p], s);
        float s1 = srow1[p];
        s1 += __shfl_xor(s1, 1, 64);
        s1 += __shfl_xor(s1, 2, 64);
        s1 += __shfl_xor(s1, 4, 64);
        s1 += __shfl_xor(s1, 8, 64);
        if (r == 0) atomicAdd(&out[rowBase + 16 + q * 4 + p], s1);
    }
}

// ---------------- fallback: round-1 VALU kernel (any size, no ws) ---------
#define BN 128
#define BM 128
#define KT 32
#define LDSS 132

__global__ __launch_bounds__(256, 4)
void kde_valu(const float* __restrict__ x, const float* __restrict__ data,
              float* __restrict__ out, int N, int M) {
    __shared__ float xs[KT][LDSS];
    __shared__ float dsh[KT][LDSS];
    __shared__ float xn_s[BN];
    __shared__ float dn_s[BM];
    const int tid = threadIdx.x;
    const int ty = tid >> 4, tx = tid & 15;
    const int rowBase = blockIdx.y * BN, colBase = blockIdx.x * BM;
    float acc[8][8];
#pragma unroll
    for (int i = 0; i < 8; ++i)
#pragma unroll
        for (int j = 0; j < 8; ++j) acc[i][j] = 0.0f;
    float normAcc = 0.0f;
    for (int kc = 0; kc < D_DIM; kc += KT) {
        __syncthreads();
#pragma unroll
        for (int i = 0; i < 4; ++i) {
            const int idx = tid + i * 256;
            const int row = idx >> 3, kq = idx & 7;
            const float4 v = *(const float4*)&x[(size_t)(rowBase + row) * D_DIM + kc + kq * 4];
            xs[kq * 4 + 0][row] = v.x; xs[kq * 4 + 1][row] = v.y;
            xs[kq * 4 + 2][row] = v.z; xs[kq * 4 + 3][row] = v.w;
            const float4 wv = *(const float4*)&data[(size_t)(colBase + row) * D_DIM + kc + kq * 4];
            dsh[kq * 4 + 0][row] = wv.x; dsh[kq * 4 + 1][row] = wv.y;
            dsh[kq * 4 + 2][row] = wv.z; dsh[kq * 4 + 3][row] = wv.w;
        }
        __syncthreads();
        {
            const float* col = (tid < 128) ? &xs[0][tid] : &dsh[0][tid - 128];
#pragma unroll
            for (int k = 0; k < KT; ++k) { const float v = col[k * LDSS]; normAcc = fmaf(v, v, normAcc); }
        }
#pragma unroll
        for (int k = 0; k < KT; ++k) {
            float a[8], b[8];
            *(float4*)&a[0] = *(const float4*)&xs[k][ty * 8];
            *(float4*)&a[4] = *(const float4*)&xs[k][ty * 8 + 4];
            *(float4*)&b[0] = *(const float4*)&dsh[k][tx * 4];
            *(float4*)&b[4] = *(const float4*)&dsh[k][64 + tx * 4];
#pragma unroll
            for (int i = 0; i < 8; ++i)
#pragma unroll
                for (int j = 0; j < 8; ++j) acc[i][j] = fmaf(a[i], b[j], acc[i][j]);
        }
    }
    if (tid < 128) xn_s[tid] = normAcc; else dn_s[tid - 128] = normAcc;
    __syncthreads();
    const float C2 = C2F;
    const float negLogM = -log2f((float)M);
#pragma unroll
    for (int i = 0; i < 8; ++i) {
        const int row = ty * 8 + i;
        const float xnr = xn_s[row];
        float s = 0.0f;
#pragma unroll
        for (int j = 0; j < 8; ++j) {
            const int col = (j < 4) ? (tx * 4 + j) : (64 + tx * 4 + (j - 4));
            const float sq = xnr + dn_s[col] - 2.0f * acc[i][j];
            s += exp2f(fmaf(-C2, sq, negLogM));
        }
#pragma unroll
        for (int off = 1; off < 16; off <<= 1) s += __shfl_xor(s, off, 64);
        if (tx == 0) atomicAdd(&out[rowBase + row], s);
    }
}

extern "C" void kernel_launch(void* const* d_in, const int* in_sizes, int n_in,
                              void* d_out, int out_size, void* d_ws, size_t ws_size,
                              hipStream_t stream) {
    const float* x    = (const float*)d_in[0];
    const float* data = (const float*)d_in[1];
    float* out = (float*)d_out;
    const int N = in_sizes[0] / D_DIM;
    const int M = in_sizes[1] / D_DIM;

    hipMemsetAsync(d_out, 0, (size_t)out_size * sizeof(float), stream);

    const size_t need = (size_t)(N + M) * D_DIM * 2 + (size_t)(N + M) * 4;
    if (ws_size < need || (N & 127) || (M & 511)) {
        dim3 grid(M / BM, N / BN);
        kde_valu<<<grid, 256, 0, stream>>>(x, data, out, N, M);
        return;
    }

    _Float16* xf = (_Float16*)d_ws;
    _Float16* df = xf + (size_t)N * D_DIM;
    float* xn_u = (float*)(df + (size_t)M * D_DIM);
    float* dn_s = xn_u + N;

    const float negLogM = -log2f((float)M);
    const int xThreads = N * 32;
    const int totThreads = (N + M) * 32;
    prep_kernel<<<totThreads / 256, 256, 0, stream>>>(x, data, xf, df, xn_u, dn_s,
                                                      xThreads, negLogM);

    const int colGroups = M / 512;           // 512 cols per group, TPG=32 tiles
    const int rowBlocks = N / 128;
    kde_f16v9<<<rowBlocks * colGroups, 256, 0, stream>>>(xf, df, xn_u, dn_s, out,
                                                         colGroups);
}